// Round 2
// baseline (13419.923 us; speedup 1.0000x reference)
//
#include <hip/hip_runtime.h>
#include <hip/hip_cooperative_groups.h>

namespace cg = cooperative_groups;

typedef unsigned short u16;
using f32x4  = __attribute__((ext_vector_type(4))) float;
using bf16x8 = __attribute__((ext_vector_type(8))) __bf16;

// ---------- helpers ----------
__device__ __forceinline__ float bf2f(u16 s){ return __builtin_bit_cast(float, (unsigned)s << 16); }
__device__ __forceinline__ float bflo(unsigned u){ return __builtin_bit_cast(float, u << 16); }
__device__ __forceinline__ float bfhi(unsigned u){ return __builtin_bit_cast(float, u & 0xffff0000u); }
__device__ __forceinline__ u16 f2bf(float f){
  unsigned u = __builtin_bit_cast(unsigned, f);
  unsigned r = u + 0x7fffu + ((u >> 16) & 1u);
  return (u16)(r >> 16);
}
// pack two fp32 -> two bf16 (round-to-nearest, ties away) in one u32
__device__ __forceinline__ unsigned pk2(float x, float y){
  unsigned ux = __builtin_bit_cast(unsigned, x) + 0x8000u;
  unsigned uy = __builtin_bit_cast(unsigned, y) + 0x8000u;
  return (ux >> 16) | (uy & 0xffff0000u);
}
__device__ __forceinline__ float tanh_f(float x){ float e = __expf(2.f*x); return 1.f - 2.f/(e + 1.f); }
__device__ __forceinline__ float sigm(float x){ return 1.f/(1.f + __expf(-x)); }
__device__ __forceinline__ f32x4 mfma16(bf16x8 a, bf16x8 b, f32x4 c){
  return __builtin_amdgcn_mfma_f32_16x16x32_bf16(a, b, c, 0, 0, 0);
}
__device__ __forceinline__ bf16x8 ldg8(const u16* p){
  return __builtin_bit_cast(bf16x8, *(const uint4*)p);
}
__device__ __forceinline__ bf16x8 cvt8(const float* p){
  float4 a = *(const float4*)p, b = *(const float4*)(p + 4);
  uint4 r; r.x = pk2(a.x, a.y); r.y = pk2(a.z, a.w); r.z = pk2(b.x, b.y); r.w = pk2(b.z, b.w);
  return __builtin_bit_cast(bf16x8, r);
}
__device__ __forceinline__ void gld(const void* g, void* l){
  __builtin_amdgcn_global_load_lds(
      (const __attribute__((address_space(1))) void*)g,
      (__attribute__((address_space(3))) void*)l, 16, 0, 0);
}

// ---------- 128x128 bf16-MFMA GEMM with fp32-or-bf16 operands:
//            C[m,n] = sum_k A[m,k]*B[n,k] (+bias[n]) ----------
// EPI 1: bf16 row-major C (ldc=N), optional fp32 bias
// EPI 2: fp32 C, fp32 bias, rows permuted m=(t*16+b) -> orow=(b*128+t)
// EPI 3: bf16 P transposed: Pt[b][n][s], b=m>>7, s=m&127
template<int EPI, bool AF32, bool BF32>
__global__ __launch_bounds__(256) void gemm_bt(
    const void* __restrict__ Av, int lda,
    const void* __restrict__ Bv, int ldb,
    void* __restrict__ Cv, const float* __restrict__ bias,
    int K, int N)
{
  constexpr int ABYTES = AF32 ? 16384 : 8192;
  constexpr int BBYTES = BF32 ? 16384 : 8192;
  __shared__ __align__(16) unsigned char lsA[ABYTES];
  __shared__ __align__(16) unsigned char lsB[BBYTES];
  const int tid = threadIdx.x;
  const int wv = tid >> 6, l = tid & 63;
  const int m0 = blockIdx.y * 128, n0 = blockIdx.x * 128;
  const int wm = wv & 1, wn = wv >> 1;
  const f32x4 vzero = {0.f, 0.f, 0.f, 0.f};
  f32x4 acc[4][4];
#pragma unroll
  for (int i = 0; i < 4; ++i)
#pragma unroll
    for (int j = 0; j < 4; ++j) acc[i][j] = vzero;

  // staging address precompute
  const float* gAf[4]; const u16* gAh[2]; void* dA[4];
  const float* gBf[4]; const u16* gBh[2]; void* dB[4];
  if constexpr (AF32){
    const float* A = (const float*)Av;
#pragma unroll
    for (int i = 0; i < 4; ++i){
      int e = (wv*4 + i)*64 + l;
      int kc = e >> 8, r = (e >> 1) & 127, h4 = (e & 1)*4;
      gAf[i] = A + (size_t)(m0 + r)*lda + kc*8 + h4;
      dA[i] = lsA + (wv*4 + i)*1024;
    }
  } else {
    const u16* A = (const u16*)Av;
#pragma unroll
    for (int i = 0; i < 2; ++i){
      int e = (wv*2 + i)*64 + l;
      int kc = e >> 7, r = e & 127;
      gAh[i] = A + (size_t)(m0 + r)*lda + kc*8;
      dA[i] = lsA + (wv*2 + i)*1024;
    }
  }
  if constexpr (BF32){
    const float* B = (const float*)Bv;
#pragma unroll
    for (int i = 0; i < 4; ++i){
      int e = (wv*4 + i)*64 + l;
      int kc = e >> 8, r = (e >> 1) & 127, h4 = (e & 1)*4;
      gBf[i] = B + (size_t)(n0 + r)*ldb + kc*8 + h4;
      dB[i] = lsB + (wv*4 + i)*1024;
    }
  } else {
    const u16* B = (const u16*)Bv;
#pragma unroll
    for (int i = 0; i < 2; ++i){
      int e = (wv*2 + i)*64 + l;
      int kc = e >> 7, r = e & 127;
      gBh[i] = B + (size_t)(n0 + r)*ldb + kc*8;
      dB[i] = lsB + (wv*2 + i)*1024;
    }
  }
  const int kq = l >> 4, li = l & 15;

  for (int k0 = 0; k0 < K; k0 += 32){
    __syncthreads();
    if constexpr (AF32){
#pragma unroll
      for (int i = 0; i < 4; ++i) gld(gAf[i] + k0, dA[i]);
    } else {
#pragma unroll
      for (int i = 0; i < 2; ++i) gld(gAh[i] + k0, dA[i]);
    }
    if constexpr (BF32){
#pragma unroll
      for (int i = 0; i < 4; ++i) gld(gBf[i] + k0, dB[i]);
    } else {
#pragma unroll
      for (int i = 0; i < 2; ++i) gld(gBh[i] + k0, dB[i]);
    }
    __syncthreads();
    bf16x8 aF[4], bF[4];
#pragma unroll
    for (int mi = 0; mi < 4; ++mi){
      int idx = kq*128 + wm*64 + mi*16 + li;
      if constexpr (AF32) aF[mi] = cvt8((const float*)lsA + idx*8);
      else                aF[mi] = ldg8((const u16*)lsA + idx*8);
    }
#pragma unroll
    for (int ni = 0; ni < 4; ++ni){
      int idx = kq*128 + wn*64 + ni*16 + li;
      if constexpr (BF32) bF[ni] = cvt8((const float*)lsB + idx*8);
      else                bF[ni] = ldg8((const u16*)lsB + idx*8);
    }
#pragma unroll
    for (int mi = 0; mi < 4; ++mi)
#pragma unroll
      for (int ni = 0; ni < 4; ++ni)
        acc[mi][ni] = mfma16(aF[mi], bF[ni], acc[mi][ni]);
  }

#pragma unroll
  for (int mi = 0; mi < 4; ++mi){
    const int mloc = wm*64 + mi*16 + kq*4;
#pragma unroll
    for (int ni = 0; ni < 4; ++ni){
      const int col = n0 + wn*64 + ni*16 + li;
      f32x4 v = acc[mi][ni];
      if constexpr (EPI == 1){
        float bb = bias ? bias[col] : 0.f;
        u16* C = (u16*)Cv;
#pragma unroll
        for (int r = 0; r < 4; ++r)
          C[(size_t)(m0 + mloc + r)*N + col] = f2bf(v[r] + bb);
      } else if constexpr (EPI == 2){
        float bb = bias[col];
        float* C = (float*)Cv;
#pragma unroll
        for (int r = 0; r < 4; ++r){
          int m = m0 + mloc + r;
          int orow = (m & 15)*128 + (m >> 4);       // (b,t) row for [B,T,V]
          C[(size_t)orow*N + col] = v[r] + bb;
        }
      } else { // EPI == 3
        u16* C = (u16*)Cv;
        int m = m0 + mloc;
        int b = m >> 7, s = m & 127;
        unsigned w0 = (unsigned)f2bf(v[0]) | ((unsigned)f2bf(v[1]) << 16);
        unsigned w1 = (unsigned)f2bf(v[2]) | ((unsigned)f2bf(v[3]) << 16);
        uint2 pk; pk.x = w0; pk.y = w1;
        *(uint2*)(C + ((size_t)b*N + col)*128 + s) = pk;
      }
    }
  }
}

// ---------- fp32 -> bf16 cast (8 elems/thread) ----------
__global__ void cast_bf(const float* __restrict__ src, u16* __restrict__ dst, int n8){
  int i = blockIdx.x*256 + threadIdx.x;
  if (i < n8){
    float4 a = ((const float4*)src)[i*2], b = ((const float4*)src)[i*2 + 1];
    uint4 r; r.x = pk2(a.x, a.y); r.y = pk2(a.z, a.w); r.z = pk2(b.x, b.y); r.w = pk2(b.z, b.w);
    ((uint4*)dst)[i] = r;
  }
}

// ---------- embedding gather + cast: e_all[t*16+b] = bf16(emb[dec_in[b,t]]) ----------
__global__ void gather_e(const int* __restrict__ tgt, const float* __restrict__ emb, u16* __restrict__ eall){
  int p = blockIdx.x;           // t*16 + b
  int t = p >> 4, b = p & 15;
  int tok = (t == 0) ? 1 : tgt[b*128 + (t - 1)];
  const float4* src = (const float4*)(emb + (size_t)tok*1024) + threadIdx.x*2;
  float4 a = src[0], c = src[1];
  uint4 r; r.x = pk2(a.x, a.y); r.y = pk2(a.z, a.w); r.z = pk2(c.x, c.y); r.w = pk2(c.z, c.w);
  ((uint4*)(eall + (size_t)p*1024))[threadIdx.x] = r;
}

__global__ void init_h(const float* __restrict__ eh, float* __restrict__ hf, u16* __restrict__ hbf){
  int i = blockIdx.x*256 + threadIdx.x;
  float v = eh[i];
  hf[i] = v;
  hbf[i] = f2bf(v);
}

// ---------- recurrent cooperative kernel ----------
struct RP {
  const u16 *Wq, *Whh, *kproj, *Pt, *ge;   // bf16
  const float *bhh, *vatt;                 // fp32 inputs
  float *q, *gh, *scores, *hf;
  u16 *hbf, *hseq;
  float *outT, *attw;
};

__global__ __launch_bounds__(256) void rec_kernel(RP p){
  cg::grid_group grid = cg::this_grid();
  __shared__ float wf[128];
  __shared__ float gcv[192];
  const int blk = blockIdx.x, tid = threadIdx.x;
  const int wv = tid >> 6, l = tid & 63;
  const int li = l & 15, kq = l >> 4;

  for (int t = 0; t < 128; ++t){
    // ---- stage A: q = h@Wq^T ; gh = h@Whh^T + bhh  (skinny MFMA, blocks 0..31) ----
    if (blk < 32){
      const u16* arow = p.hbf + li*1024 + kq*8;     // A[m=li][k]
      const int nb = blk*128 + wv*32;
      const bool isQ = (nb < 1024);
      const u16* wb = isQ ? p.Wq : p.Whh;
      const int nrel = isQ ? nb : (nb - 1024);
      const u16* br0 = wb + (size_t)(nrel + li)*1024 + kq*8;
      const u16* br1 = wb + (size_t)(nrel + 16 + li)*1024 + kq*8;
      f32x4 c00 = {0.f,0.f,0.f,0.f}, c01 = {0.f,0.f,0.f,0.f};
      f32x4 c10 = {0.f,0.f,0.f,0.f}, c11 = {0.f,0.f,0.f,0.f};
#pragma unroll 4
      for (int k0 = 0; k0 < 1024; k0 += 64){
        bf16x8 aA = ldg8(arow + k0);
        bf16x8 aB = ldg8(arow + k0 + 32);
        c00 = mfma16(aA, ldg8(br0 + k0), c00);
        c01 = mfma16(aB, ldg8(br0 + k0 + 32), c01);
        c10 = mfma16(aA, ldg8(br1 + k0), c10);
        c11 = mfma16(aB, ldg8(br1 + k0 + 32), c11);
      }
      f32x4 cA = c00 + c01, cB = c10 + c11;
#pragma unroll
      for (int ni = 0; ni < 2; ++ni){
        f32x4 c = ni ? cB : cA;
        int n = nb + ni*16 + li;
#pragma unroll
        for (int r = 0; r < 4; ++r){
          int b = kq*4 + r;
          if (isQ) p.q[b*1024 + n] = c[r];
          else     p.gh[b*3072 + (n - 1024)] = c[r] + p.bhh[n - 1024];
        }
      }
    }
    grid.sync();

    // ---- stage B: scores[b,s] = sum_h v[h]*tanh(q[b,h] + kproj[b,s,h]) ----
    {
      const int b = blk >> 4, sg = blk & 15;
#pragma unroll
      for (int si = 0; si < 2; ++si){
        int s = sg*8 + wv*2 + si;
        const uint4* kp = (const uint4*)(p.kproj + ((size_t)(b*128 + s))*1024) + l*2;
        const float4* qp = (const float4*)(p.q + b*1024) + l*4;
        const float4* vp = (const float4*)(p.vatt) + l*4;
        uint4 ka = kp[0], kb = kp[1];
        float4 v0 = vp[0], v1 = vp[1], v2 = vp[2], v3 = vp[3];
        float4 q0 = qp[0], q1 = qp[1], q2 = qp[2], q3 = qp[3];
        float acc = 0.f;
        acc += v0.x*tanh_f(q0.x + bflo(ka.x)) + v0.y*tanh_f(q0.y + bfhi(ka.x));
        acc += v0.z*tanh_f(q0.z + bflo(ka.y)) + v0.w*tanh_f(q0.w + bfhi(ka.y));
        acc += v1.x*tanh_f(q1.x + bflo(ka.z)) + v1.y*tanh_f(q1.y + bfhi(ka.z));
        acc += v1.z*tanh_f(q1.z + bflo(ka.w)) + v1.w*tanh_f(q1.w + bfhi(ka.w));
        acc += v2.x*tanh_f(q2.x + bflo(kb.x)) + v2.y*tanh_f(q2.y + bfhi(kb.x));
        acc += v2.z*tanh_f(q2.z + bflo(kb.y)) + v2.w*tanh_f(q2.w + bfhi(kb.y));
        acc += v3.x*tanh_f(q3.x + bflo(kb.z)) + v3.y*tanh_f(q3.y + bfhi(kb.z));
        acc += v3.z*tanh_f(q3.z + bflo(kb.w)) + v3.w*tanh_f(q3.w + bfhi(kb.w));
#pragma unroll
        for (int o = 32; o; o >>= 1) acc += __shfl_xor(acc, o);
        if (l == 0) p.scores[b*128 + s] = acc;
      }
    }
    grid.sync();

    // ---- stage C: softmax + gc (via P) + GRU update ----
    {
      const int b = blk >> 4, ic = blk & 15;
      if (wv == 0){
        float x0 = p.scores[b*128 + l], x1 = p.scores[b*128 + 64 + l];
        float m = fmaxf(x0, x1);
#pragma unroll
        for (int o = 32; o; o >>= 1) m = fmaxf(m, __shfl_xor(m, o));
        float e0 = __expf(x0 - m), e1 = __expf(x1 - m);
        float sm = e0 + e1;
#pragma unroll
        for (int o = 32; o; o >>= 1) sm += __shfl_xor(sm, o);
        float inv = 1.f / sm;
        wf[l] = e0*inv; wf[64 + l] = e1*inv;
      }
      __syncthreads();
      if (tid < 192){
        int gate = tid >> 6, ii = tid & 63;
        int j = gate*1024 + ic*64 + ii;
        const uint4* pr = (const uint4*)(p.Pt + ((size_t)(b*3072 + j))*128);
        float acc = 0.f;
#pragma unroll
        for (int c = 0; c < 16; ++c){
          uint4 u = pr[c];
          const float* w8 = &wf[c*8];
          acc += w8[0]*bflo(u.x) + w8[1]*bfhi(u.x)
               + w8[2]*bflo(u.y) + w8[3]*bfhi(u.y)
               + w8[4]*bflo(u.z) + w8[5]*bfhi(u.z)
               + w8[6]*bflo(u.w) + w8[7]*bfhi(u.w);
        }
        gcv[tid] = acc;
      }
      __syncthreads();
      if (tid < 64){
        int i = ic*64 + tid;
        size_t mrow = (size_t)(t*16 + b);
        const u16* gep = p.ge + mrow*3072;
        float ger = bf2f(gep[i]), gez = bf2f(gep[i + 1024]), gen = bf2f(gep[i + 2048]);
        const float* ghp = p.gh + b*3072;
        float ghr = ghp[i], ghz = ghp[i + 1024], ghn = ghp[i + 2048];
        float r = sigm(ger + gcv[tid] + ghr);
        float z = sigm(gez + gcv[64 + tid] + ghz);
        float n = tanh_f(gen + gcv[128 + tid] + r*ghn);
        float hp = p.hf[b*1024 + i];
        float hn = (1.f - z)*n + z*hp;
        p.hf[b*1024 + i] = hn;
        u16 hb = f2bf(hn);
        p.hbf[b*1024 + i] = hb;
        p.hseq[mrow*1024 + i] = hb;
        if (t == 127) p.outT[b*1024 + i] = hn;
      }
      if (ic == 0 && tid < 128){
        p.attw[((size_t)(b*128 + t))*128 + tid] = wf[tid];
      }
    }
    grid.sync();
  }
}

// ---------- logsumexp over V per output row, then in-place fixup ----------
__global__ __launch_bounds__(256) void lse_kernel(const float* __restrict__ outp, float* __restrict__ lse){
  __shared__ float rm[256], rs[256];
  int r = blockIdx.x, tid = threadIdx.x;
  const float4* rp = (const float4*)(outp + (size_t)r*32000);
  float m = -3.0e38f, s = 0.f;
  for (int v = tid; v < 8000; v += 256){
    float4 x = rp[v];
    float mx = fmaxf(fmaxf(x.x, x.y), fmaxf(x.z, x.w));
    if (mx > m){ s *= __expf(m - mx); m = mx; }
    s += __expf(x.x - m) + __expf(x.y - m) + __expf(x.z - m) + __expf(x.w - m);
  }
  rm[tid] = m; rs[tid] = s;
  __syncthreads();
  for (int o = 128; o; o >>= 1){
    if (tid < o){
      float m2 = rm[tid + o], s2 = rs[tid + o], m1 = rm[tid], s1 = rs[tid];
      float M = fmaxf(m1, m2);
      rs[tid] = s1*__expf(m1 - M) + s2*__expf(m2 - M);
      rm[tid] = M;
    }
    __syncthreads();
  }
  if (tid == 0) lse[r] = rm[0] + __logf(rs[0]);
}

__global__ __launch_bounds__(256) void fixup_kernel(float* __restrict__ outp, const float* __restrict__ lse){
  int idx = blockIdx.x*256 + threadIdx.x;   // 16,384,000 float4 total
  int r = idx / 8000;                       // 8000 float4 per row
  float L = lse[r];
  float4* p4 = (float4*)outp;
  float4 u = p4[idx];
  u.x -= L; u.y -= L; u.z -= L; u.w -= L;
  p4[idx] = u;
}

// ---------- host ----------
extern "C" void kernel_launch(void* const* d_in, const int* in_sizes, int n_in,
                              void* d_out, int out_size, void* d_ws, size_t ws_size,
                              hipStream_t stream) {
  (void)in_sizes; (void)n_in; (void)out_size; (void)ws_size;
  const float* eo   = (const float*)d_in[0];   // [16][128][1024]
  const float* eh   = (const float*)d_in[1];   // [1][16][1024]
  const int*   tgt  = (const int*)d_in[2];     // [16][128]
  const float* emb  = (const float*)d_in[3];   // [32000][1024]
  const float* Wq   = (const float*)d_in[4];   // [1024][1024]
  const float* Wk   = (const float*)d_in[5];   // [1024][1024]
  const float* vatt = (const float*)d_in[6];   // [1024]
  const float* Wih  = (const float*)d_in[7];   // [3072][2048]
  const float* Whh  = (const float*)d_in[8];   // [3072][1024]
  const float* bih  = (const float*)d_in[9];   // [3072]
  const float* bhh  = (const float*)d_in[10];  // [3072]
  const float* Wout = (const float*)d_in[11];  // [32000][1024]
  const float* bout = (const float*)d_in[12];  // [32000]
  float* out = (float*)d_out;

  char* ws = (char*)d_ws;
  u16*  kproj = (u16*) (ws + 0);          //  4 MiB  [16*128][1024] bf16
  u16*  ge    = (u16*) (ws + 4194304);    // 12 MiB  [128*16][3072] bf16 (incl b_ih)
  u16*  Pt    = (u16*) (ws + 16777216);   // 12 MiB  [16][3072][128] bf16
  u16*  eall  = (u16*) (ws + 29360128);   //  4 MiB  [128*16][1024] bf16
  u16*  hseq  = (u16*) (ws + 33554432);   //  4 MiB  [128*16][1024] bf16
  u16*  wqb   = (u16*) (ws + 37748736);   //  2 MiB  bf16 Wq
  u16*  whhb  = (u16*) (ws + 39845888);   //  6 MiB  bf16 Whh
  float* hf   = (float*)(ws + 46137344);  // 64 KiB  [16][1024] f32
  u16*  hbf   = (u16*) (ws + 46202880);   // 32 KiB
  float* q    = (float*)(ws + 46235648);  // 64 KiB
  float* gh   = (float*)(ws + 46301184);  // 192 KiB
  float* sc   = (float*)(ws + 46497792);  //  8 KiB
  float* lse  = (float*)(ws + 46505984);  //  8 KiB

  float* outT = out + 65536000;  // hT  [1][16][1024] fp32
  float* attw = out + 65552384;  // attw [16][128][128] fp32

  cast_bf<<<512, 256, 0, stream>>>(Wq, wqb, 131072);
  cast_bf<<<1536, 256, 0, stream>>>(Whh, whhb, 393216);
  gather_e<<<2048, 128, 0, stream>>>(tgt, emb, eall);
  init_h<<<64, 256, 0, stream>>>(eh, hf, hbf);

  // kproj = eo @ Wk^T  (A fp32, B fp32 -> bf16 out)
  gemm_bt<1, true, true><<<dim3(8, 16), 256, 0, stream>>>(eo, 1024, Wk, 1024, kproj, nullptr, 1024, 1024);
  // ge_all = e @ W_ih[:, :H]^T + b_ih  (A bf16, B fp32 -> bf16 out)
  gemm_bt<1, false, true><<<dim3(24, 16), 256, 0, stream>>>(eall, 1024, Wih, 2048, ge, bih, 1024, 3072);
  // Pt[b][j][s] = (eo @ W_ih[:, H:]^T)[b*128+s, j]  (A fp32, B fp32 -> bf16 out, transposed)
  gemm_bt<3, true, true><<<dim3(24, 16), 256, 0, stream>>>(eo, 1024, Wih + 1024, 2048, Pt, nullptr, 1024, 3072);

  RP rp;
  rp.Wq = wqb; rp.Whh = whhb; rp.kproj = kproj; rp.Pt = Pt; rp.ge = ge;
  rp.bhh = bhh; rp.vatt = vatt;
  rp.q = q; rp.gh = gh; rp.scores = sc; rp.hf = hf;
  rp.hbf = hbf; rp.hseq = hseq; rp.outT = outT; rp.attw = attw;
  void* kargs[] = { (void*)&rp };
  hipLaunchCooperativeKernel((void*)rec_kernel, dim3(256), dim3(256), kargs, 0, stream);

  // logits (fp32, +b_out) -> d_out rows permuted to [B,T,V]  (A bf16, B fp32)
  gemm_bt<2, false, true><<<dim3(250, 16), 256, 0, stream>>>(hseq, 1024, Wout, 1024, out, bout, 1024, 32000);
  lse_kernel<<<2048, 256, 0, stream>>>(out, lse);
  fixup_kernel<<<64000, 256, 0, stream>>>(out, lse);
}